// Round 7
// baseline (172.449 us; speedup 1.0000x reference)
//
#include <hip/hip_runtime.h>
#include <math.h>

// FFTConvReservoir: y = tanh(ifft(fft(u)*fft(K)).real + D*u); B=8,H=256,L=8192 fp32.
// Round 7: NT=256 / 32-elem-per-thread structure (R3, best so far) with:
//  - LDS as ONE interleaved float2 array -> ds_read_b64/ds_write_b64: halves LDS
//    instruction count (576->288/thread) and address math.
//  - float2-granular swizzle PH(e)=e^((e>>4)&15): all three pass patterns verified
//    conflict-free per 16-lane quarter-wave.
//  - address arrays computed once per pass, reused read+write.
//  - kw=(FFT(K)+D)/N folded in kfft (R6 win: u read exactly once, epilogue = tanh).
//  - shared pyramid across both 16-elem groups; kf loaded just before use (R3 style).
// Lessons kept: no __launch_bounds__ occupancy arg (R5 spill disaster); no whole-kernel
// kf prefetch (R5); fusion into one kernel regresses (R4).

#define LL 8192
#define NT 256
#define HH 256
#define TWO_PI 6.2831853071795864f
#define CP16 0.980785280403230f  // cos(pi/16)
#define SP16 0.195090322016128f  // sin(pi/16)
#define CP8  0.92387953251129f   // cos(pi/8)
#define SP8  0.38268343236509f   // sin(pi/8)

__device__ __forceinline__ int PH(int e) { return e ^ ((e >> 4) & 15); }

__device__ __forceinline__ float fast_tanh(float x) {
    float e = __expf(2.0f * x);
    return 1.0f - 2.0f / (e + 1.0f);
}

// Twiddle pyramid: level j at offset (1<<j)-1, length 2^j; top level chained cmul,
// lower levels by squaring.
template<int JT>
__device__ __forceinline__ void fill_pyr_cs(float c0, float s0, float Er, float Ei,
                                            float* twr, float* twi) {
    const int off = (1 << JT) - 1;
    twr[off] = c0; twi[off] = s0;
    #pragma unroll
    for (int m = 1; m < (1 << JT); ++m) {
        const float pr = twr[off + m - 1], pi = twi[off + m - 1];
        twr[off + m] = pr * Er - pi * Ei;
        twi[off + m] = pr * Ei + pi * Er;
    }
    #pragma unroll
    for (int j = JT - 1; j >= 0; --j) {
        #pragma unroll
        for (int m = 0; m < (1 << j); ++m) {
            const float a = twr[(2 << j) - 1 + m], b = twi[(2 << j) - 1 + m];
            twr[(1 << j) - 1 + m] = a * a - b * b;
            twi[(1 << j) - 1 + m] = 2.0f * a * b;
        }
    }
}
template<int JT>
__device__ __forceinline__ void fill_pyr(float ang0, float Er, float Ei,
                                         float* twr, float* twi) {
    float s, c;
    __sincosf(ang0, &s, &c);
    fill_pyr_cs<JT>(c, s, Er, Ei, twr, twi);
}

template<int R2>
__device__ __forceinline__ void dif_apply(float* xr, float* xi,
                                          const float* twr, const float* twi) {
    #pragma unroll
    for (int j = R2 - 1; j >= 0; --j) {
        #pragma unroll
        for (int q = 0; q < (1 << (R2 - 1)); ++q) {
            const int mm = q & ((1 << j) - 1);
            const int m0 = ((q >> j) << (j + 1)) | mm;
            const int m1 = m0 + (1 << j);
            const float wr = twr[(1 << j) - 1 + mm], wi = twi[(1 << j) - 1 + mm];
            const float ar = xr[m0], ai = xi[m0], br = xr[m1], bi = xi[m1];
            xr[m0] = ar + br; xi[m0] = ai + bi;
            const float dr = ar - br, di = ai - bi;
            xr[m1] = dr * wr - di * wi;
            xi[m1] = dr * wi + di * wr;
        }
    }
}
template<int R2>
__device__ __forceinline__ void dit_apply(float* xr, float* xi,
                                          const float* twr, const float* twi) {
    #pragma unroll
    for (int j = 0; j < R2; ++j) {
        #pragma unroll
        for (int q = 0; q < (1 << (R2 - 1)); ++q) {
            const int mm = q & ((1 << j) - 1);
            const int m0 = ((q >> j) << (j + 1)) | mm;
            const int m1 = m0 + (1 << j);
            const float wr = twr[(1 << j) - 1 + mm], wi = twi[(1 << j) - 1 + mm];
            const float br = xr[m1] * wr - xi[m1] * wi;
            const float bi = xr[m1] * wi + xi[m1] * wr;
            const float ar = xr[m0], ai = xi[m0];
            xr[m0] = ar + br; xi[m0] = ai + bi;
            xr[m1] = ar - br; xi[m1] = ai - bi;
        }
    }
}

// Fwd pass A (stages 12..8): xr/xi = natural elements [tid + 256m]; writes LDS b64.
__device__ __forceinline__ void fwd_A(float* xr, float* xi, int tid, float2* buf) {
    float twr[31], twi[31];
    fill_pyr<4>(-(TWO_PI / 8192.0f) * (float)tid, CP16, -SP16, twr, twi);
    dif_apply<5>(xr, xi, twr, twi);
    #pragma unroll
    for (int m = 0; m < 32; ++m) {
        buf[PH(tid + (m << 8))] = make_float2(xr[m], xi[m]);
    }
}

// Fwd pass B (stages 7..4), both groups; shared pyramid; addr array reused r+w.
__device__ __forceinline__ void fwd_B(int tid, float2* buf) {
    int pa[2][16];
    float xr[2][16], xi[2][16], twr[15], twi[15];
    #pragma unroll
    for (int gg = 0; gg < 2; ++gg) {
        const int g = tid + (gg << 8);
        const int base = ((g >> 4) << 8) | (g & 15);
        #pragma unroll
        for (int m = 0; m < 16; ++m) {
            pa[gg][m] = PH(base + (m << 4));
            const float2 v = buf[pa[gg][m]];
            xr[gg][m] = v.x; xi[gg][m] = v.y;
        }
    }
    fill_pyr<3>(-(TWO_PI / 256.0f) * (float)(tid & 15), CP8, -SP8, twr, twi);
    dif_apply<4>(xr[0], xi[0], twr, twi);
    dif_apply<4>(xr[1], xi[1], twr, twi);
    #pragma unroll
    for (int gg = 0; gg < 2; ++gg) {
        #pragma unroll
        for (int m = 0; m < 16; ++m) {
            buf[pa[gg][m]] = make_float2(xr[gg][m], xi[gg][m]);
        }
    }
}

// Inv pass B' (stages 4..7, conjugate twiddles).
__device__ __forceinline__ void inv_B(int tid, float2* buf) {
    int pa[2][16];
    float xr[2][16], xi[2][16], twr[15], twi[15];
    #pragma unroll
    for (int gg = 0; gg < 2; ++gg) {
        const int g = tid + (gg << 8);
        const int base = ((g >> 4) << 8) | (g & 15);
        #pragma unroll
        for (int m = 0; m < 16; ++m) {
            pa[gg][m] = PH(base + (m << 4));
            const float2 v = buf[pa[gg][m]];
            xr[gg][m] = v.x; xi[gg][m] = v.y;
        }
    }
    fill_pyr<3>((TWO_PI / 256.0f) * (float)(tid & 15), CP8, SP8, twr, twi);
    dit_apply<4>(xr[0], xi[0], twr, twi);
    dit_apply<4>(xr[1], xi[1], twr, twi);
    #pragma unroll
    for (int gg = 0; gg < 2; ++gg) {
        #pragma unroll
        for (int m = 0; m < 16; ++m) {
            buf[pa[gg][m]] = make_float2(xr[gg][m], xi[gg][m]);
        }
    }
}

__global__ __launch_bounds__(NT) void kfft_kernel(const float* __restrict__ K,
                                                  const float* __restrict__ D,
                                                  float2* __restrict__ Kf) {
    __shared__ float2 buf[LL];
    const int h = blockIdx.x;
    const int tid = threadIdx.x;
    const float* Kr = K + (size_t)h * LL;
    float xr[32], xi[32];
    #pragma unroll
    for (int m = 0; m < 32; ++m) {
        xr[m] = Kr[tid + (m << 8)];
        xi[m] = 0.0f;
    }
    fwd_A(xr, xi, tid, buf);
    __syncthreads();
    fwd_B(tid, buf);
    __syncthreads();
    // Pass C (stages 3..0) + fold kw = (X + D[h])/N; store in conv's consumption layout.
    const float dh = D[h];
    const float invN = 1.0f / (float)LL;
    float2* outp = Kf + (size_t)h * LL;
    float twr[15], twi[15];
    fill_pyr_cs<3>(1.0f, 0.0f, CP8, -SP8, twr, twi);
    #pragma unroll
    for (int gg = 0; gg < 2; ++gg) {
        const int i0 = tid + (gg << 8);
        const int base = i0 << 4;
        float yr[16], yi[16];
        #pragma unroll
        for (int m = 0; m < 16; ++m) {
            const float2 v = buf[PH(base + m)];
            yr[m] = v.x; yi[m] = v.y;
        }
        dif_apply<4>(yr, yi, twr, twi);
        #pragma unroll
        for (int m = 0; m < 16; ++m) {
            outp[(m << 9) + i0] = make_float2((yr[m] + dh) * invN, yi[m] * invN);
        }
    }
}

__global__ __launch_bounds__(NT) void conv_kernel(const float* __restrict__ u,
                                                  const float2* __restrict__ Kf,
                                                  float* __restrict__ out) {
    __shared__ float2 buf[LL];
    const int tid = threadIdx.x;
    const int h = blockIdx.x & (HH - 1);
    const int pr_ = blockIdx.x >> 8;        // batch pair 0..3
    const size_t off0 = ((size_t)(pr_ * 2) * HH + h) * LL;
    const size_t off1 = off0 + (size_t)HH * LL;
    const float* u0 = u + off0;
    const float* u1 = u + off1;

    float xr[32], xi[32];
    #pragma unroll
    for (int m = 0; m < 32; ++m) {
        xr[m] = u0[tid + (m << 8)];
        xi[m] = u1[tid + (m << 8)];
    }
    fwd_A(xr, xi, tid, buf);          // z = u0 + i*u1
    __syncthreads();
    fwd_B(tid, buf);
    __syncthreads();

    // Merged pass C: fwd stages 3..0, pointwise * kw, inv stages 0..3.
    {
        const float2* kf = Kf + (size_t)h * LL;
        int pc[2][16];
        float yr[2][16], yi[2][16], twr[15], twi[15];
        #pragma unroll
        for (int gg = 0; gg < 2; ++gg) {
            const int base = (tid + (gg << 8)) << 4;
            #pragma unroll
            for (int m = 0; m < 16; ++m) {
                pc[gg][m] = PH(base + m);
                const float2 v = buf[pc[gg][m]];
                yr[gg][m] = v.x; yi[gg][m] = v.y;
            }
        }
        fill_pyr_cs<3>(1.0f, 0.0f, CP8, -SP8, twr, twi);
        dif_apply<4>(yr[0], yi[0], twr, twi);
        dif_apply<4>(yr[1], yi[1], twr, twi);
        #pragma unroll
        for (int gg = 0; gg < 2; ++gg) {
            const int i0 = tid + (gg << 8);
            #pragma unroll
            for (int m = 0; m < 16; ++m) {
                const float2 w = kf[(m << 9) + i0];
                const float a = yr[gg][m], b = yi[gg][m];
                yr[gg][m] = a * w.x - b * w.y;
                yi[gg][m] = a * w.y + b * w.x;
            }
        }
        fill_pyr_cs<3>(1.0f, 0.0f, CP8, SP8, twr, twi);
        dit_apply<4>(yr[0], yi[0], twr, twi);
        dit_apply<4>(yr[1], yi[1], twr, twi);
        #pragma unroll
        for (int gg = 0; gg < 2; ++gg) {
            #pragma unroll
            for (int m = 0; m < 16; ++m) {
                buf[pc[gg][m]] = make_float2(yr[gg][m], yi[gg][m]);
            }
        }
    }
    __syncthreads();

    inv_B(tid, buf);
    __syncthreads();

    // Inv pass A' (stages 8..12) + epilogue (skip/norm folded into kw).
    {
        float twr[31], twi[31];
        #pragma unroll
        for (int m = 0; m < 32; ++m) {
            const float2 v = buf[PH(tid + (m << 8))];
            xr[m] = v.x; xi[m] = v.y;
        }
        fill_pyr<4>((TWO_PI / 8192.0f) * (float)tid, CP16, SP16, twr, twi);
        dit_apply<5>(xr, xi, twr, twi);
    }
    float* o0 = out + off0;
    float* o1 = out + off1;
    #pragma unroll
    for (int m = 0; m < 32; ++m) {
        const int n = tid + (m << 8);
        o0[n] = fast_tanh(xr[m]);
        o1[n] = fast_tanh(xi[m]);
    }
}

extern "C" void kernel_launch(void* const* d_in, const int* in_sizes, int n_in,
                              void* d_out, int out_size, void* d_ws, size_t ws_size,
                              hipStream_t stream) {
    const float* u = (const float*)d_in[0];   // (8, 256, 8192)
    const float* K = (const float*)d_in[1];   // (256, 8192)
    const float* D = (const float*)d_in[2];   // (256,)
    float* out = (float*)d_out;               // (8, 256, 8192)
    float2* Kf = (float2*)d_ws;               // 256 * 8192 float2 = 16 MB

    kfft_kernel<<<dim3(HH), dim3(NT), 0, stream>>>(K, D, Kf);
    conv_kernel<<<dim3(4 * HH), dim3(NT), 0, stream>>>(u, Kf, out);
}

// Round 8
// 153.201 us; speedup vs baseline: 1.1256x; 1.1256x over previous
//
#include <hip/hip_runtime.h>
#include <math.h>

// FFTConvReservoir: y = tanh(ifft(fft(u)*fft(K)).real + D*u); B=8,H=256,L=8192 fp32.
// Round 8: R3 arithmetic (best: scalar b32 LDS, NT=256, 32 elem/thread) restructured
// for WAVE-PRIVATE middle: after DIF stages 12..8, the FFT splits into 32 independent
// 256-pt sub-FFTs on contiguous chunks; each wave owns 8 chunks exclusively, so
// stages 7..0, *kw, inverse 0..7 run with NO __syncthreads (same-wave LDS ordering is
// compiler-handled). Barriers 4 -> 2. kw is per-lane-contiguous in the M2 layout ->
// dwordx4 loads, prefetched a full pass ahead. Unified swizzle SW(e) keeps all three
// access patterns exactly 2-way (free).
// Lessons kept: no b64 LDS (R7), no launch_bounds occupancy arg (R5), no single-kernel
// fusion (R4), kw=(FFT(K)+D)/N folded in kfft (R6).

#define LL 8192
#define NT 256
#define HH 256
#define TWO_PI 6.2831853071795864f
#define CP16 0.980785280403230f  // cos(pi/16)
#define SP16 0.195090322016128f  // sin(pi/16)
#define CP8  0.92387953251129f   // cos(pi/8)
#define SP8  0.38268343236509f   // sin(pi/8)

// Bank swizzle: verified 2-way (free) for stride-256 (A), stride-16 (M1),
// contiguous-16 (M2) patterns with separate re/im b32 arrays.
__device__ __forceinline__ int SW(int e) {
    return e ^ ((e >> 4) & 15) ^ (((e >> 8) & 1) << 4);
}
__device__ __forceinline__ float fast_tanh(float x) {
    float e = __expf(2.0f * x);
    return 1.0f - 2.0f / (e + 1.0f);
}

// Twiddle pyramid: level j at offset (1<<j)-1, length 2^j; top level chained cmul,
// lower levels by squaring.
template<int JT>
__device__ __forceinline__ void fill_pyr_cs(float c0, float s0, float Er, float Ei,
                                            float* twr, float* twi) {
    const int off = (1 << JT) - 1;
    twr[off] = c0; twi[off] = s0;
    #pragma unroll
    for (int m = 1; m < (1 << JT); ++m) {
        const float pr = twr[off + m - 1], pi = twi[off + m - 1];
        twr[off + m] = pr * Er - pi * Ei;
        twi[off + m] = pr * Ei + pi * Er;
    }
    #pragma unroll
    for (int j = JT - 1; j >= 0; --j) {
        #pragma unroll
        for (int m = 0; m < (1 << j); ++m) {
            const float a = twr[(2 << j) - 1 + m], b = twi[(2 << j) - 1 + m];
            twr[(1 << j) - 1 + m] = a * a - b * b;
            twi[(1 << j) - 1 + m] = 2.0f * a * b;
        }
    }
}
template<int JT>
__device__ __forceinline__ void fill_pyr(float ang0, float Er, float Ei,
                                         float* twr, float* twi) {
    float s, c;
    __sincosf(ang0, &s, &c);
    fill_pyr_cs<JT>(c, s, Er, Ei, twr, twi);
}

template<int R2>
__device__ __forceinline__ void dif_apply(float* xr, float* xi,
                                          const float* twr, const float* twi) {
    #pragma unroll
    for (int j = R2 - 1; j >= 0; --j) {
        #pragma unroll
        for (int q = 0; q < (1 << (R2 - 1)); ++q) {
            const int mm = q & ((1 << j) - 1);
            const int m0 = ((q >> j) << (j + 1)) | mm;
            const int m1 = m0 + (1 << j);
            const float wr = twr[(1 << j) - 1 + mm], wi = twi[(1 << j) - 1 + mm];
            const float ar = xr[m0], ai = xi[m0], br = xr[m1], bi = xi[m1];
            xr[m0] = ar + br; xi[m0] = ai + bi;
            const float dr = ar - br, di = ai - bi;
            xr[m1] = dr * wr - di * wi;
            xi[m1] = dr * wi + di * wr;
        }
    }
}
template<int R2>
__device__ __forceinline__ void dit_apply(float* xr, float* xi,
                                          const float* twr, const float* twi) {
    #pragma unroll
    for (int j = 0; j < R2; ++j) {
        #pragma unroll
        for (int q = 0; q < (1 << (R2 - 1)); ++q) {
            const int mm = q & ((1 << j) - 1);
            const int m0 = ((q >> j) << (j + 1)) | mm;
            const int m1 = m0 + (1 << j);
            const float wr = twr[(1 << j) - 1 + mm], wi = twi[(1 << j) - 1 + mm];
            const float br = xr[m1] * wr - xi[m1] * wi;
            const float bi = xr[m1] * wi + xi[m1] * wr;
            const float ar = xr[m0], ai = xi[m0];
            xr[m0] = ar + br; xi[m0] = ai + bi;
            xr[m1] = ar - br; xi[m1] = ai - bi;
        }
    }
}

// Fwd pass A (stages 12..8): xr/xi = natural elements [tid + 256m]; writes LDS.
__device__ __forceinline__ void fwd_A(float* xr, float* xi, int tid,
                                      float* re, float* im) {
    float twr[31], twi[31];
    fill_pyr<4>(-(TWO_PI / 8192.0f) * (float)tid, CP16, -SP16, twr, twi);
    dif_apply<5>(xr, xi, twr, twi);
    #pragma unroll
    for (int m = 0; m < 32; ++m) {
        const int p = SW(tid + (m << 8));
        re[p] = xr[m]; im[p] = xi[m];
    }
}

__global__ __launch_bounds__(NT) void kfft_kernel(const float* __restrict__ K,
                                                  const float* __restrict__ D,
                                                  float2* __restrict__ Kf) {
    __shared__ float re[LL];
    __shared__ float im[LL];
    const int h = blockIdx.x;
    const int tid = threadIdx.x;
    const float* Kr = K + (size_t)h * LL;
    float xr[32], xi[32];
    #pragma unroll
    for (int m = 0; m < 32; ++m) {
        xr[m] = Kr[tid + (m << 8)];
        xi[m] = 0.0f;
    }
    fwd_A(xr, xi, tid, re, im);
    __syncthreads();

    const int lane = tid & 63, wv = tid >> 6;
    const int q = lane & 15, qw = (lane >> 4) & 3;

    // M1 (stages 7..4), wave-private chunks, 2 rounds; shared pyramid (q fixed).
    {
        float twr[15], twi[15];
        fill_pyr<3>(-(TWO_PI / 256.0f) * (float)q, CP8, -SP8, twr, twi);
        #pragma unroll
        for (int r = 0; r < 2; ++r) {
            const int c = (wv << 3) + qw + (r << 2);
            const int base = (c << 8) + q;
            float ar[16], ai[16];
            #pragma unroll
            for (int m = 0; m < 16; ++m) {
                const int p = SW(base + (m << 4));
                ar[m] = re[p]; ai[m] = im[p];
            }
            dif_apply<4>(ar, ai, twr, twi);
            #pragma unroll
            for (int m = 0; m < 16; ++m) {
                const int p = SW(base + (m << 4));
                re[p] = ar[m]; im[p] = ai[m];
            }
        }
    }
    // M2 (stages 3..0) + fold kw = (X + D[h])/N; per-lane contiguous dwordx4 stores.
    {
        const float dh = D[h];
        const float invN = 1.0f / (float)LL;
        float twr[15], twi[15];
        fill_pyr_cs<3>(1.0f, 0.0f, CP8, -SP8, twr, twi);
        #pragma unroll
        for (int r = 0; r < 2; ++r) {
            const int c = (wv << 3) + qw + (r << 2);
            const int eb = (c << 8) + (q << 4);
            float yr[16], yi[16];
            #pragma unroll
            for (int j = 0; j < 16; ++j) {
                const int p = SW(eb + j);
                yr[j] = re[p]; yi[j] = im[p];
            }
            dif_apply<4>(yr, yi, twr, twi);
            float4* o4 = (float4*)(Kf + (size_t)h * LL + eb);
            #pragma unroll
            for (int jj = 0; jj < 8; ++jj) {
                float4 v;
                v.x = (yr[2 * jj]     + dh) * invN; v.y = yi[2 * jj]     * invN;
                v.z = (yr[2 * jj + 1] + dh) * invN; v.w = yi[2 * jj + 1] * invN;
                o4[jj] = v;
            }
        }
    }
}

__global__ __launch_bounds__(NT) void conv_kernel(const float* __restrict__ u,
                                                  const float2* __restrict__ Kf,
                                                  float* __restrict__ out) {
    __shared__ float re[LL];
    __shared__ float im[LL];
    const int tid = threadIdx.x;
    const int h = blockIdx.x & (HH - 1);
    const int pr_ = blockIdx.x >> 8;        // batch pair 0..3
    const size_t off0 = ((size_t)(pr_ * 2) * HH + h) * LL;
    const size_t off1 = off0 + (size_t)HH * LL;
    const float* u0 = u + off0;
    const float* u1 = u + off1;

    float xr[32], xi[32];
    #pragma unroll
    for (int m = 0; m < 32; ++m) {
        xr[m] = u0[tid + (m << 8)];
        xi[m] = u1[tid + (m << 8)];
    }
    fwd_A(xr, xi, tid, re, im);       // z = u0 + i*u1
    __syncthreads();

    const int lane = tid & 63, wv = tid >> 6;
    const int q = lane & 15, qw = (lane >> 4) & 3;
    const int c0 = (wv << 3) + qw;          // round-0 chunk; round-1 = c0+4
    const float2* kf = Kf + (size_t)h * LL;

    // ---- wave-private middle: no __syncthreads until pass A' ----
    // kw prefetch for both rounds (dwordx4, per-lane contiguous 128B), consumed in M2
    // a full M1 pass later.
    float kwr[2][16], kwi[2][16];
    #pragma unroll
    for (int r = 0; r < 2; ++r) {
        const int eb = ((c0 + (r << 2)) << 8) + (q << 4);
        const float4* kp = (const float4*)(kf + eb);
        #pragma unroll
        for (int jj = 0; jj < 8; ++jj) {
            const float4 v = kp[jj];
            kwr[r][2 * jj] = v.x;     kwi[r][2 * jj] = v.y;
            kwr[r][2 * jj + 1] = v.z; kwi[r][2 * jj + 1] = v.w;
        }
    }

    // M1 (stages 7..4), 2 rounds, shared pyramid.
    {
        float twr[15], twi[15];
        fill_pyr<3>(-(TWO_PI / 256.0f) * (float)q, CP8, -SP8, twr, twi);
        #pragma unroll
        for (int r = 0; r < 2; ++r) {
            const int base = ((c0 + (r << 2)) << 8) + q;
            float ar[16], ai[16];
            #pragma unroll
            for (int m = 0; m < 16; ++m) {
                const int p = SW(base + (m << 4));
                ar[m] = re[p]; ai[m] = im[p];
            }
            dif_apply<4>(ar, ai, twr, twi);
            #pragma unroll
            for (int m = 0; m < 16; ++m) {
                const int p = SW(base + (m << 4));
                re[p] = ar[m]; im[p] = ai[m];
            }
        }
    }
    // Merged M2: stages 3..0, *kw, inverse stages 0..3. 2 rounds, shared pyramids.
    {
        float twd_r[15], twd_i[15], twu_r[15], twu_i[15];
        fill_pyr_cs<3>(1.0f, 0.0f, CP8, -SP8, twd_r, twd_i);
        fill_pyr_cs<3>(1.0f, 0.0f, CP8, SP8, twu_r, twu_i);
        #pragma unroll
        for (int r = 0; r < 2; ++r) {
            const int eb = ((c0 + (r << 2)) << 8) + (q << 4);
            float yr[16], yi[16];
            #pragma unroll
            for (int j = 0; j < 16; ++j) {
                const int p = SW(eb + j);
                yr[j] = re[p]; yi[j] = im[p];
            }
            dif_apply<4>(yr, yi, twd_r, twd_i);
            #pragma unroll
            for (int j = 0; j < 16; ++j) {
                const float a = yr[j], b = yi[j];
                yr[j] = a * kwr[r][j] - b * kwi[r][j];
                yi[j] = a * kwi[r][j] + b * kwr[r][j];
            }
            dit_apply<4>(yr, yi, twu_r, twu_i);
            #pragma unroll
            for (int j = 0; j < 16; ++j) {
                const int p = SW(eb + j);
                re[p] = yr[j]; im[p] = yi[j];
            }
        }
    }
    // M1' (inverse stages 4..7), 2 rounds, shared pyramid.
    {
        float twr[15], twi[15];
        fill_pyr<3>((TWO_PI / 256.0f) * (float)q, CP8, SP8, twr, twi);
        #pragma unroll
        for (int r = 0; r < 2; ++r) {
            const int base = ((c0 + (r << 2)) << 8) + q;
            float ar[16], ai[16];
            #pragma unroll
            for (int m = 0; m < 16; ++m) {
                const int p = SW(base + (m << 4));
                ar[m] = re[p]; ai[m] = im[p];
            }
            dit_apply<4>(ar, ai, twr, twi);
            #pragma unroll
            for (int m = 0; m < 16; ++m) {
                const int p = SW(base + (m << 4));
                re[p] = ar[m]; im[p] = ai[m];
            }
        }
    }
    __syncthreads();

    // Inv pass A' (stages 8..12) + epilogue (skip/norm folded into kw).
    {
        float twr[31], twi[31];
        #pragma unroll
        for (int m = 0; m < 32; ++m) {
            const int p = SW(tid + (m << 8));
            xr[m] = re[p]; xi[m] = im[p];
        }
        fill_pyr<4>((TWO_PI / 8192.0f) * (float)tid, CP16, SP16, twr, twi);
        dit_apply<5>(xr, xi, twr, twi);
    }
    float* o0 = out + off0;
    float* o1 = out + off1;
    #pragma unroll
    for (int m = 0; m < 32; ++m) {
        const int n = tid + (m << 8);
        o0[n] = fast_tanh(xr[m]);
        o1[n] = fast_tanh(xi[m]);
    }
}

extern "C" void kernel_launch(void* const* d_in, const int* in_sizes, int n_in,
                              void* d_out, int out_size, void* d_ws, size_t ws_size,
                              hipStream_t stream) {
    const float* u = (const float*)d_in[0];   // (8, 256, 8192)
    const float* K = (const float*)d_in[1];   // (256, 8192)
    const float* D = (const float*)d_in[2];   // (256,)
    float* out = (float*)d_out;               // (8, 256, 8192)
    float2* Kf = (float2*)d_ws;               // 256 * 8192 float2 = 16 MB

    kfft_kernel<<<dim3(HH), dim3(NT), 0, stream>>>(K, D, Kf);
    conv_kernel<<<dim3(4 * HH), dim3(NT), 0, stream>>>(u, Kf, out);
}